// Round 1
// baseline (1581.777 us; speedup 1.0000x reference)
//
#include <hip/hip_runtime.h>
#include <cstdint>
#include <cstddef>

#define CDIM 192
#define HEADS 6
#define CH 32          // head dim
#define HW 65536       // 256*256
#define WIMG 256
#define NPIX 262144    // 4*65536
#define QKV_STRIDE 50331648ull  // floats per q/k/v buffer: 4096*6*32*64

// Layouts:
//  q,k,v : [win(4096)][head(6)][c(32)][t(64)]   (t contiguous)
//  AO    : [pix(262144)][ch(192)]               (channel contiguous, pixel-major)

// ---------------------------------------------------------------------------
// Kernel A: qkv = W(576x192) @ x + b, scattered into window layout.
// Grid: x = 9*512 (ot = bx%9, pt = bx/9), y = batch. Block 256.
// p-tile = 8 rows x 16 cols = two 8x8 windows. o-tile = 64.
__global__ __launch_bounds__(256) void qkv_proj(
    const float* __restrict__ x, const float* __restrict__ wq,
    const float* __restrict__ bias,
    float* __restrict__ qg, float* __restrict__ kg, float* __restrict__ vg)
{
  __shared__ float Wl[16][64];
  __shared__ float Xl[16][128];
  const int tid = threadIdx.x;
  const int ot = blockIdx.x % 9;
  const int pt = blockIdx.x / 9;
  const int b  = blockIdx.y;
  const int h0 = (pt >> 4) << 3;   // spatial row base
  const int w0 = (pt & 15) << 4;   // spatial col base (16 wide)
  const float* xb = x + (size_t)b * CDIM * HW;
  const int to = tid >> 4, tp = tid & 15;

  float acc[4][8];
#pragma unroll
  for (int a = 0; a < 4; ++a)
#pragma unroll
    for (int p = 0; p < 8; ++p) acc[a][p] = 0.f;

  for (int k0 = 0; k0 < CDIM; k0 += 16) {
    // stage W tile 64o x 16c (transposed -> Wl[c][o])
    float4 wv = *(const float4*)(wq + (size_t)(ot * 64 + (tid >> 2)) * CDIM + k0 + ((tid & 3) << 2));
    {
      int cb = (tid & 3) << 2, oc = tid >> 2;
      Wl[cb + 0][oc] = wv.x; Wl[cb + 1][oc] = wv.y;
      Wl[cb + 2][oc] = wv.z; Wl[cb + 3][oc] = wv.w;
    }
    // stage X tile 16c x 128p
#pragma unroll
    for (int rep = 0; rep < 2; ++rep) {
      int e = (tid << 2) + (rep << 10);
      int c = e >> 7, pr = e & 127;
      int r = pr >> 4, ww = pr & 15;
      float4 xv = *(const float4*)(xb + (size_t)(k0 + c) * HW + (h0 + r) * WIMG + w0 + ww);
      *(float4*)&Xl[c][pr] = xv;
    }
    __syncthreads();
#pragma unroll
    for (int kk = 0; kk < 16; ++kk) {
      float av[4], xv8[8];
      *(float4*)av       = *(float4*)&Wl[kk][to << 2];
      *(float4*)xv8      = *(float4*)&Xl[kk][tp << 3];
      *(float4*)(xv8 + 4) = *(float4*)&Xl[kk][(tp << 3) + 4];
#pragma unroll
      for (int a = 0; a < 4; ++a)
#pragma unroll
        for (int p = 0; p < 8; ++p) acc[a][p] += av[a] * xv8[p];
    }
    __syncthreads();
  }

  // epilogue: scatter into q/k/v window layout [win][head][c][t]
  const int o0 = ot * 64 + (to << 2);          // 4 consecutive o, same sel/head
  const int sel = o0 / CDIM;
  const int oo = o0 - sel * CDIM;
  const int head = oo >> 5, c0 = oo & 31;
  const int win = (b << 10) + (pt >> 4) * 32 + ((pt & 15) << 1) + (tp & 1);
  const int t0 = (tp >> 1) << 3;               // window-row * 8
  float* dst = (sel == 0) ? qg : ((sel == 1) ? kg : vg);
  float* base = dst + (size_t)(win * HEADS + head) * (CH * 64) + t0;
#pragma unroll
  for (int a = 0; a < 4; ++a) {
    float bb = bias[o0 + a];
    float4 v0 = make_float4(acc[a][0] + bb, acc[a][1] + bb, acc[a][2] + bb, acc[a][3] + bb);
    float4 v1 = make_float4(acc[a][4] + bb, acc[a][5] + bb, acc[a][6] + bb, acc[a][7] + bb);
    *(float4*)(base + (c0 + a) * 64)     = v0;
    *(float4*)(base + (c0 + a) * 64 + 4) = v1;
  }
}

// ---------------------------------------------------------------------------
// Kernel B: attention for one (win, head) per block. 256 threads.
__global__ __launch_bounds__(256) void win_attn(
    const float* __restrict__ qg, const float* __restrict__ kg,
    const float* __restrict__ vg, const float* __restrict__ rpe,
    float* __restrict__ AO)
{
  __shared__ float ql[32][68], kl[32][68], vl[32][68];
  __shared__ float at[64][68];
  __shared__ float rp[225];
  const int tid = threadIdx.x;
  const int wh = blockIdx.x;               // win*6 + head
  const int win = wh / HEADS;
  const int head = wh - win * HEADS;
  const float* qb = qg + (size_t)wh * (CH * 64);
  const float* kb = kg + (size_t)wh * (CH * 64);
  const float* vb = vg + (size_t)wh * (CH * 64);

#pragma unroll
  for (int rep = 0; rep < 2; ++rep) {
    int e = (tid << 2) + (rep << 10);
    int c = e >> 6, i = e & 63;
    *(float4*)&ql[c][i] = *(const float4*)(qb + e);
    *(float4*)&kl[c][i] = *(const float4*)(kb + e);
    *(float4*)&vl[c][i] = *(const float4*)(vb + e);
  }
  for (int i = tid; i < 225; i += 256) rp[i] = rpe[head * 225 + i];
  __syncthreads();

  // scores: 4x4 tile per thread. rows i0..i0+3, cols j0..j0+3
  const int ty = tid >> 4, tx = tid & 15;
  const int i0 = ty << 2, j0 = tx << 2;
  float s[4][4] = {{0.f}};
  for (int c = 0; c < 32; ++c) {
    float q4[4], k4[4];
    *(float4*)q4 = *(float4*)&ql[c][i0];
    *(float4*)k4 = *(float4*)&kl[c][j0];
#pragma unroll
    for (int a = 0; a < 4; ++a)
#pragma unroll
      for (int jj = 0; jj < 4; ++jj) s[a][jj] += q4[a] * k4[jj];
  }
  const float scale = 0.17677669529663687f;  // 32^-0.5
#pragma unroll
  for (int a = 0; a < 4; ++a) {
    const int i = i0 + a;
    const int ih = i >> 3, iw = i & 7;
    float m = -1e30f;
#pragma unroll
    for (int jj = 0; jj < 4; ++jj) {
      int j = j0 + jj;
      int dh = (j >> 3) - ih + 7, dw = (j & 7) - iw + 7;
      s[a][jj] = s[a][jj] * scale + rp[dh * 15 + dw];
      m = fmaxf(m, s[a][jj]);
    }
    // row reduce across the 16 lanes sharing this i-range (contiguous lanes)
    m = fmaxf(m, __shfl_xor(m, 8, 16));
    m = fmaxf(m, __shfl_xor(m, 4, 16));
    m = fmaxf(m, __shfl_xor(m, 2, 16));
    m = fmaxf(m, __shfl_xor(m, 1, 16));
    float sum = 0.f;
#pragma unroll
    for (int jj = 0; jj < 4; ++jj) { s[a][jj] = __expf(s[a][jj] - m); sum += s[a][jj]; }
    sum += __shfl_xor(sum, 8, 16);
    sum += __shfl_xor(sum, 4, 16);
    sum += __shfl_xor(sum, 2, 16);
    sum += __shfl_xor(sum, 1, 16);
    const float inv = 1.f / sum;
    *(float4*)&at[i][j0] = make_float4(s[a][0] * inv, s[a][1] * inv, s[a][2] * inv, s[a][3] * inv);
  }
  __syncthreads();

  // AV: out[i][c] = sum_j at[i][j] * vl[c][j]. Tile: 4 i x 2 c per thread.
  const int ti = tid >> 4, tc = tid & 15;
  const int i0b = ti << 2, c0 = tc << 1;
  float acc2[4][2] = {{0.f}};
  for (int jc = 0; jc < 16; ++jc) {
    float a0[4], a1[4], a2[4], a3[4], v0[4], v1[4];
    *(float4*)a0 = *(float4*)&at[i0b + 0][jc << 2];
    *(float4*)a1 = *(float4*)&at[i0b + 1][jc << 2];
    *(float4*)a2 = *(float4*)&at[i0b + 2][jc << 2];
    *(float4*)a3 = *(float4*)&at[i0b + 3][jc << 2];
    *(float4*)v0 = *(float4*)&vl[c0 + 0][jc << 2];
    *(float4*)v1 = *(float4*)&vl[c0 + 1][jc << 2];
#pragma unroll
    for (int jj = 0; jj < 4; ++jj) {
      acc2[0][0] += a0[jj] * v0[jj]; acc2[0][1] += a0[jj] * v1[jj];
      acc2[1][0] += a1[jj] * v0[jj]; acc2[1][1] += a1[jj] * v1[jj];
      acc2[2][0] += a2[jj] * v0[jj]; acc2[2][1] += a2[jj] * v1[jj];
      acc2[3][0] += a3[jj] * v0[jj]; acc2[3][1] += a3[jj] * v1[jj];
    }
  }
  // write AO pixel-major: AO[pix][head*32 + c0 .. +1]
  const int bimg = win >> 10, rem = win & 1023;
  const int h0 = (rem >> 5) << 3, w0c = (rem & 31) << 3;
  const int pix0 = (bimg << 16) + (h0 + (i0b >> 3)) * WIMG + w0c + (i0b & 7);
#pragma unroll
  for (int rr = 0; rr < 4; ++rr) {
    *(float2*)(AO + (size_t)(pix0 + rr) * CDIM + head * CH + c0) =
        make_float2(acc2[rr][0], acc2[rr][1]);
  }
}

// ---------------------------------------------------------------------------
// Kernel C: out = W2(192x192) @ AO + b2, AO is pixel-major (transposed GEMM B).
// Grid: x = 3*512 (ot = bx%3, pt = bx/3), y = batch. Block 256.
__global__ __launch_bounds__(256) void out_proj(
    const float* __restrict__ AO, const float* __restrict__ wo,
    const float* __restrict__ bias, float* __restrict__ out)
{
  __shared__ float Wl[16][64];
  __shared__ float Xl[16][132];
  const int tid = threadIdx.x;
  const int ot = blockIdx.x % 3;
  const int pt = blockIdx.x / 3;   // 0..511: 128 consecutive pixels in a row
  const int b  = blockIdx.y;
  const int h = pt >> 1;
  const int w0 = (pt & 1) << 7;
  const size_t pixbase = (size_t)b * HW + (size_t)h * WIMG + w0;
  const int to = tid >> 4, tp = tid & 15;

  float acc[4][8];
#pragma unroll
  for (int a = 0; a < 4; ++a)
#pragma unroll
    for (int p = 0; p < 8; ++p) acc[a][p] = 0.f;

  for (int k0 = 0; k0 < CDIM; k0 += 16) {
    float4 wv = *(const float4*)(wo + (size_t)(ot * 64 + (tid >> 2)) * CDIM + k0 + ((tid & 3) << 2));
    {
      int cb = (tid & 3) << 2, oc = tid >> 2;
      Wl[cb + 0][oc] = wv.x; Wl[cb + 1][oc] = wv.y;
      Wl[cb + 2][oc] = wv.z; Wl[cb + 3][oc] = wv.w;
    }
#pragma unroll
    for (int rep = 0; rep < 2; ++rep) {
      int e = (tid << 2) + (rep << 10);
      int p = e >> 4, c4 = e & 15;   // 128 pixels x 16 channels, channel-quads
      float4 xv = *(const float4*)(AO + (pixbase + p) * CDIM + k0 + c4);
      Xl[c4 + 0][p] = xv.x; Xl[c4 + 1][p] = xv.y;
      Xl[c4 + 2][p] = xv.z; Xl[c4 + 3][p] = xv.w;
    }
    __syncthreads();
#pragma unroll
    for (int kk = 0; kk < 16; ++kk) {
      float av[4], xv8[8];
      *(float4*)av        = *(float4*)&Wl[kk][to << 2];
      *(float4*)xv8       = *(float4*)&Xl[kk][tp << 3];
      *(float4*)(xv8 + 4) = *(float4*)&Xl[kk][(tp << 3) + 4];
#pragma unroll
      for (int a = 0; a < 4; ++a)
#pragma unroll
        for (int p = 0; p < 8; ++p) acc[a][p] += av[a] * xv8[p];
    }
    __syncthreads();
  }

  const int o0 = ot * 64 + (to << 2);
  float* ob = out + (size_t)b * CDIM * HW + (size_t)o0 * HW + (size_t)h * WIMG + w0 + (tp << 3);
#pragma unroll
  for (int a = 0; a < 4; ++a) {
    float bb = bias[o0 + a];
    *(float4*)(ob + (size_t)a * HW)     = make_float4(acc[a][0] + bb, acc[a][1] + bb, acc[a][2] + bb, acc[a][3] + bb);
    *(float4*)(ob + (size_t)a * HW + 4) = make_float4(acc[a][4] + bb, acc[a][5] + bb, acc[a][6] + bb, acc[a][7] + bb);
  }
}

// ---------------------------------------------------------------------------
extern "C" void kernel_launch(void* const* d_in, const int* in_sizes, int n_in,
                              void* d_out, int out_size, void* d_ws, size_t ws_size,
                              hipStream_t stream) {
  const float* x      = (const float*)d_in[0];
  const float* qkv_w  = (const float*)d_in[1];
  const float* qkv_b  = (const float*)d_in[2];
  const float* out_w  = (const float*)d_in[3];
  const float* out_b  = (const float*)d_in[4];
  const float* rpe    = (const float*)d_in[5];
  float* out = (float*)d_out;

  float* q  = (float*)d_ws;
  float* k  = q + QKV_STRIDE;
  float* v  = k + QKV_STRIDE;
  float* AO = v + QKV_STRIDE;

  qkv_proj<<<dim3(9 * 512, 4), 256, 0, stream>>>(x, qkv_w, qkv_b, q, k, v);
  win_attn<<<dim3(4096 * HEADS), 256, 0, stream>>>(q, k, v, rpe, AO);
  out_proj<<<dim3(3 * 512, 4), 256, 0, stream>>>(AO, out_w, out_b, out);
}

// Round 2
// 754.649 us; speedup vs baseline: 2.0960x; 2.0960x over previous
//
#include <hip/hip_runtime.h>
#include <cstdint>
#include <cstddef>

typedef __attribute__((ext_vector_type(8))) short short8;
typedef __attribute__((ext_vector_type(4))) float floatx4;

#define SEG 50331648ull   // elements per 100MB bf16 segment (= xb,q,k,v,AO sizes)

__device__ __forceinline__ unsigned short bf16rne(float f) {
  union { float f; unsigned int u; } c; c.f = f;
  unsigned int u = c.u;
  return (unsigned short)((u + 0x7fffu + ((u >> 16) & 1u)) >> 16);
}
__device__ __forceinline__ unsigned int packbf(float a, float b) {
  return (unsigned int)bf16rne(a) | ((unsigned int)bf16rne(b) << 16);
}

// ---------------------------------------------------------------------------
// P0: x[b][c][65536] fp32  ->  xb[b][pix][192] bf16   (transpose + convert)
// grid (1024 p-tiles, 3 c-chunks, 4 b), block 256
__global__ __launch_bounds__(256) void x_to_bf16(const float* __restrict__ x,
                                                 unsigned short* __restrict__ xb) {
  __shared__ float Tl[64][65];
  const int tid = threadIdx.x;
  const int ptile = blockIdx.x, cc = blockIdx.y, b = blockIdx.z;
  const float* src = x + ((size_t)(b * 192 + cc * 64)) * 65536 + ptile * 64;
  {
    int row = tid >> 2;            // c within chunk
    int cb = (tid & 3) * 4;
#pragma unroll
    for (int rr = 0; rr < 4; ++rr) {
      int col = cb + rr * 16;      // p within tile
      float4 v = *(const float4*)(src + (size_t)row * 65536 + col);
      *(float4*)&Tl[row][col] = v;
    }
  }
  __syncthreads();
  unsigned short* dst = xb + ((size_t)b * 65536 + (size_t)ptile * 64) * 192 + cc * 64;
  {
    int p_l = tid >> 2;
    int c0 = (tid & 3) * 16;
    unsigned int w[8];
#pragma unroll
    for (int e = 0; e < 8; ++e)
      w[e] = packbf(Tl[c0 + 2 * e][p_l], Tl[c0 + 2 * e + 1][p_l]);
    *(uint4*)(dst + (size_t)p_l * 192 + c0)     = make_uint4(w[0], w[1], w[2], w[3]);
    *(uint4*)(dst + (size_t)p_l * 192 + c0 + 8) = make_uint4(w[4], w[5], w[6], w[7]);
  }
}

// ---------------------------------------------------------------------------
// P1: expand rpe into MFMA C/D fragment layout: bias_d[head][it*4+jt][lane][reg]
__global__ void bias_prep(const float* __restrict__ rpe, float* __restrict__ bias_d) {
  const int head = blockIdx.x;
  const int tid = threadIdx.x;
  for (int e = tid; e < 1024; e += 256) {
    int it = e >> 8, jt = (e >> 6) & 3, ln = e & 63;
    int quad = ln >> 4, n = ln & 15;
    int j = jt * 16 + n;
    int jh = j >> 3, jw = j & 7;
    float4 out;
    float* o = (float*)&out;
#pragma unroll
    for (int r = 0; r < 4; ++r) {
      int m = it * 16 + quad * 4 + r;
      int idx = (jh - (m >> 3) + 7) * 15 + (jw - (m & 7) + 7);
      o[r] = rpe[head * 225 + idx];
    }
    *(float4*)(bias_d + ((size_t)(head * 16 + it * 4 + jt) * 64 + ln) * 4) = out;
  }
}

// ---------------------------------------------------------------------------
// Kernel A: qkv = W(576x192) @ xb^T, MFMA bf16. A=W (m=o), B=xb (n=p).
// Output q,k,v: [win*6+head][t(64)][c(32)] bf16; q pre-scaled by 32^-0.5.
// grid (9 o-tiles, 256 p-tiles(=image row), 4 b), block 256.
#define WPAD 200
#define XPAD 40
__global__ __launch_bounds__(256) void qkv_mm(
    const unsigned short* __restrict__ xb, const float* __restrict__ wq,
    const float* __restrict__ qkv_b,
    unsigned short* __restrict__ q, unsigned short* __restrict__ k,
    unsigned short* __restrict__ v) {
  __shared__ unsigned short Wl[64 * WPAD];
  __shared__ unsigned short Xl[256 * XPAD];
  const int tid = threadIdx.x;
  const int ot = blockIdx.x, pt = blockIdx.y, b = blockIdx.z;
  const int o0 = ot * 64;
  {  // stage W tile 64o x 192c -> bf16
    int o = tid >> 2, cb = (tid & 3) * 4;
    const float* wr = wq + (size_t)(o0 + o) * 192;
#pragma unroll
    for (int r = 0; r < 12; ++r) {
      int c = cb + r * 16;
      float4 wv = *(const float4*)(wr + c);
      *(uint2*)&Wl[o * WPAD + c] = make_uint2(packbf(wv.x, wv.y), packbf(wv.z, wv.w));
    }
  }
  const int lane = tid & 63, w = tid >> 6;
  const int n16 = lane & 15, quad = lane >> 4;
  floatx4 acc[4][4];
  const floatx4 fz = {0.f, 0.f, 0.f, 0.f};
#pragma unroll
  for (int i = 0; i < 4; ++i)
#pragma unroll
    for (int j = 0; j < 4; ++j) acc[i][j] = fz;

  const unsigned short* xrow = xb + ((size_t)b * 65536 + (size_t)pt * 256) * 192;
  for (int k0 = 0; k0 < 192; k0 += 32) {
#pragma unroll
    for (int pass = 0; pass < 4; ++pass) {
      int p_l = pass * 64 + (tid >> 2);
      int ch = tid & 3;
      short8 xv = *(const short8*)(xrow + (size_t)p_l * 192 + k0 + ch * 8);
      *(short8*)&Xl[p_l * XPAD + ch * 8] = xv;
    }
    __syncthreads();
    short8 a[4], bf[4];
#pragma unroll
    for (int i = 0; i < 4; ++i)
      a[i] = *(const short8*)&Wl[(16 * i + n16) * WPAD + k0 + quad * 8];
#pragma unroll
    for (int j = 0; j < 4; ++j)
      bf[j] = *(const short8*)&Xl[(w * 64 + 16 * j + n16) * XPAD + quad * 8];
#pragma unroll
    for (int i = 0; i < 4; ++i)
#pragma unroll
      for (int j = 0; j < 4; ++j)
        acc[i][j] = __builtin_amdgcn_mfma_f32_16x16x32_bf16(a[i], bf[j], acc[i][j], 0, 0, 0);
    __syncthreads();
  }
  // epilogue: D[o][p] -> q/k/v [wh][t][c]
  const int sel = ot / 3;
  unsigned short* dst = (sel == 0) ? q : ((sel == 1) ? k : v);
  const float scl = (sel == 0) ? 0.17677669529663687f : 1.0f;
  const int hwin = pt >> 3, hin = pt & 7;
#pragma unroll
  for (int j = 0; j < 4; ++j) {
    int wcol = w * 64 + 16 * j + n16;
    int win = (b << 10) + hwin * 32 + (wcol >> 3);
    int t = hin * 8 + (wcol & 7);
#pragma unroll
    for (int i = 0; i < 4; ++i) {
      int og = o0 + 16 * i + quad * 4;
      int off = og - sel * 192;
      int head = off >> 5, c = off & 31;
      float4 bb = *(const float4*)(qkv_b + og);
      float v0 = (acc[i][j][0] + bb.x) * scl;
      float v1 = (acc[i][j][1] + bb.y) * scl;
      float v2 = (acc[i][j][2] + bb.z) * scl;
      float v3 = (acc[i][j][3] + bb.w) * scl;
      *(uint2*)(dst + ((size_t)(win * 6 + head) * 64 + t) * 32 + c) =
          make_uint2(packbf(v0, v1), packbf(v2, v3));
    }
  }
}

// ---------------------------------------------------------------------------
// Kernel B: window attention, one wave per (win,head). No __syncthreads.
// Q/K/V fragments straight from global ([t][c] layout == fragment layout).
__global__ __launch_bounds__(256) void attn(
    const unsigned short* __restrict__ q, const unsigned short* __restrict__ k,
    const unsigned short* __restrict__ v, const float* __restrict__ bias_d,
    unsigned short* __restrict__ AO) {
  __shared__ unsigned short pl[4][64 * 72];   // P in [t][j]; later aliased as O [t][c] (64*40)
  __shared__ unsigned short vl[4][32 * 72];   // V transposed [c][t]
  const int tid = threadIdx.x, w = tid >> 6, lane = tid & 63;
  const int n16 = lane & 15, quad = lane >> 4;
  const int wh = blockIdx.x * 4 + w;
  const int win = wh / 6, head = wh - win * 6;
  const unsigned short* qb = q + (size_t)wh * 2048;
  const unsigned short* kb = k + (size_t)wh * 2048;
  const unsigned short* vb = v + (size_t)wh * 2048;

  // issue V row load early (row t = lane, 32 c)
  short8 vrow[4];
#pragma unroll
  for (int c8 = 0; c8 < 4; ++c8)
    vrow[c8] = *(const short8*)(vb + lane * 32 + c8 * 8);

  short8 aq[4], bk[4];
#pragma unroll
  for (int it = 0; it < 4; ++it)
    aq[it] = *(const short8*)(qb + (16 * it + n16) * 32 + quad * 8);
#pragma unroll
  for (int jt = 0; jt < 4; ++jt)
    bk[jt] = *(const short8*)(kb + (16 * jt + n16) * 32 + quad * 8);

  // V transpose into LDS [c][t]
  unsigned short* vlw = (unsigned short*)vl[w];
#pragma unroll
  for (int c8 = 0; c8 < 4; ++c8)
#pragma unroll
    for (int e = 0; e < 8; ++e)
      vlw[(c8 * 8 + e) * 72 + lane] = (unsigned short)vrow[c8][e];

  // S = (q*scale) K^T  (scale folded into q)
  floatx4 s[4][4];
  const floatx4 fz = {0.f, 0.f, 0.f, 0.f};
#pragma unroll
  for (int it = 0; it < 4; ++it)
#pragma unroll
    for (int jt = 0; jt < 4; ++jt)
      s[it][jt] = __builtin_amdgcn_mfma_f32_16x16x32_bf16(aq[it], bk[jt], fz, 0, 0, 0);

  // softmax rows (m = 16it + 4quad + r), bias from precomputed frag-layout table
  const float* bD = bias_d + (size_t)head * 4096;
  unsigned short* plw = (unsigned short*)pl[w];
#pragma unroll
  for (int it = 0; it < 4; ++it) {
    floatx4 bb[4];
#pragma unroll
    for (int jt = 0; jt < 4; ++jt)
      bb[jt] = *(const floatx4*)(bD + ((size_t)(it * 4 + jt) * 64 + lane) * 4);
#pragma unroll
    for (int r = 0; r < 4; ++r) {
      float x0 = s[it][0][r] + bb[0][r];
      float x1 = s[it][1][r] + bb[1][r];
      float x2 = s[it][2][r] + bb[2][r];
      float x3 = s[it][3][r] + bb[3][r];
      float m = fmaxf(fmaxf(x0, x1), fmaxf(x2, x3));
      m = fmaxf(m, __shfl_xor(m, 1));
      m = fmaxf(m, __shfl_xor(m, 2));
      m = fmaxf(m, __shfl_xor(m, 4));
      m = fmaxf(m, __shfl_xor(m, 8));
      float e0 = __expf(x0 - m), e1 = __expf(x1 - m);
      float e2 = __expf(x2 - m), e3 = __expf(x3 - m);
      float sum = e0 + e1 + e2 + e3;
      sum += __shfl_xor(sum, 1);
      sum += __shfl_xor(sum, 2);
      sum += __shfl_xor(sum, 4);
      sum += __shfl_xor(sum, 8);
      float inv = 1.0f / sum;
      int mr = it * 16 + quad * 4 + r;
      plw[mr * 72 + 0 * 16 + n16] = bf16rne(e0 * inv);
      plw[mr * 72 + 1 * 16 + n16] = bf16rne(e1 * inv);
      plw[mr * 72 + 2 * 16 + n16] = bf16rne(e2 * inv);
      plw[mr * 72 + 3 * 16 + n16] = bf16rne(e3 * inv);
    }
  }

  // O = P V : A=P from pl, B=V from vl
  short8 bv[2][2], ap[4][2];
#pragma unroll
  for (int ct = 0; ct < 2; ++ct)
#pragma unroll
    for (int kk = 0; kk < 2; ++kk)
      bv[ct][kk] = *(const short8*)&vlw[(16 * ct + n16) * 72 + kk * 32 + quad * 8];
#pragma unroll
  for (int it = 0; it < 4; ++it)
#pragma unroll
    for (int kk = 0; kk < 2; ++kk)
      ap[it][kk] = *(const short8*)&plw[(16 * it + n16) * 72 + kk * 32 + quad * 8];
  floatx4 o[4][2];
#pragma unroll
  for (int it = 0; it < 4; ++it)
#pragma unroll
    for (int ct = 0; ct < 2; ++ct) {
      floatx4 acc = __builtin_amdgcn_mfma_f32_16x16x32_bf16(ap[it][0], bv[ct][0], fz, 0, 0, 0);
      o[it][ct] = __builtin_amdgcn_mfma_f32_16x16x32_bf16(ap[it][1], bv[ct][1], acc, 0, 0, 0);
    }

  // stage O [t][c] into LDS (aliases pl; pl is dead after ap reads)
  unsigned short* ol = plw;  // [64][40]
#pragma unroll
  for (int it = 0; it < 4; ++it)
#pragma unroll
    for (int ct = 0; ct < 2; ++ct)
#pragma unroll
      for (int r = 0; r < 4; ++r)
        ol[(16 * it + quad * 4 + r) * 40 + 16 * ct + n16] = bf16rne(o[it][ct][r]);

  // write AO[pix][192] rows (row t = lane)
  const int t = lane;
  const int bimg = win >> 10, rem = win & 1023;
  const int h0 = (rem >> 5) << 3, w0 = (rem & 31) << 3;
  const size_t pix = ((size_t)bimg << 16) + (size_t)(h0 + (t >> 3)) * 256 + w0 + (t & 7);
  unsigned short* dstp = AO + pix * 192 + head * 32;
#pragma unroll
  for (int c8 = 0; c8 < 4; ++c8)
    *(short8*)(dstp + c8 * 8) = *(const short8*)&ol[t * 40 + c8 * 8];
}

// ---------------------------------------------------------------------------
// Kernel C: out = W2(192x192) @ AO^T. A=AO (m=p), B=W2 (n=o) -> D[p][o],
// coalesced float4 stores. grid (3 o-tiles, 256 p-tiles, 4 b), block 256.
__global__ __launch_bounds__(256) void out_mm(
    const unsigned short* __restrict__ AO, const float* __restrict__ w2,
    const float* __restrict__ b2, float* __restrict__ out) {
  __shared__ unsigned short Wl[64 * WPAD];
  __shared__ unsigned short Xl[256 * XPAD];
  const int tid = threadIdx.x;
  const int ox = blockIdx.x, pt = blockIdx.y, b = blockIdx.z;
  const int o0 = ox * 64;
  {
    int o = tid >> 2, cb = (tid & 3) * 4;
    const float* wr = w2 + (size_t)(o0 + o) * 192;
#pragma unroll
    for (int r = 0; r < 12; ++r) {
      int c = cb + r * 16;
      float4 wv = *(const float4*)(wr + c);
      *(uint2*)&Wl[o * WPAD + c] = make_uint2(packbf(wv.x, wv.y), packbf(wv.z, wv.w));
    }
  }
  const int lane = tid & 63, w = tid >> 6;
  const int n16 = lane & 15, quad = lane >> 4;
  floatx4 acc[4][4];
  const floatx4 fz = {0.f, 0.f, 0.f, 0.f};
#pragma unroll
  for (int i = 0; i < 4; ++i)
#pragma unroll
    for (int j = 0; j < 4; ++j) acc[i][j] = fz;

  const unsigned short* arow = AO + ((size_t)b * 65536 + (size_t)pt * 256) * 192;
  for (int k0 = 0; k0 < 192; k0 += 32) {
#pragma unroll
    for (int pass = 0; pass < 4; ++pass) {
      int p_l = pass * 64 + (tid >> 2);
      int ch = tid & 3;
      short8 xv = *(const short8*)(arow + (size_t)p_l * 192 + k0 + ch * 8);
      *(short8*)&Xl[p_l * XPAD + ch * 8] = xv;
    }
    __syncthreads();
    short8 a[4], bf[4];
#pragma unroll
    for (int i = 0; i < 4; ++i)
      a[i] = *(const short8*)&Xl[(w * 64 + 16 * i + n16) * XPAD + quad * 8];
#pragma unroll
    for (int j = 0; j < 4; ++j)
      bf[j] = *(const short8*)&Wl[(16 * j + n16) * WPAD + k0 + quad * 8];
#pragma unroll
    for (int i = 0; i < 4; ++i)
#pragma unroll
      for (int j = 0; j < 4; ++j)
        acc[i][j] = __builtin_amdgcn_mfma_f32_16x16x32_bf16(a[i], bf[j], acc[i][j], 0, 0, 0);
    __syncthreads();
  }
#pragma unroll
  for (int j = 0; j < 4; ++j) {
    int o = o0 + 16 * j + n16;
    float bj = b2[o];
    float* obase = out + ((size_t)b * 192 + o) * 65536 + (size_t)pt * 256;
#pragma unroll
    for (int i = 0; i < 4; ++i) {
      int p = w * 64 + 16 * i + quad * 4;
      *(float4*)(obase + p) = make_float4(acc[i][j][0] + bj, acc[i][j][1] + bj,
                                          acc[i][j][2] + bj, acc[i][j][3] + bj);
    }
  }
}

// ---------------------------------------------------------------------------
extern "C" void kernel_launch(void* const* d_in, const int* in_sizes, int n_in,
                              void* d_out, int out_size, void* d_ws, size_t ws_size,
                              hipStream_t stream) {
  const float* x     = (const float*)d_in[0];
  const float* qkv_w = (const float*)d_in[1];
  const float* qkv_b = (const float*)d_in[2];
  const float* out_w = (const float*)d_in[3];
  const float* out_b = (const float*)d_in[4];
  const float* rpe   = (const float*)d_in[5];
  float* out = (float*)d_out;

  unsigned short* xb = (unsigned short*)d_ws;
  unsigned short* q  = xb + SEG;
  unsigned short* k  = q + SEG;
  unsigned short* v  = k + SEG;
  unsigned short* AO = v + SEG;
  float* bias_d = (float*)(AO + SEG);

  x_to_bf16<<<dim3(1024, 3, 4), 256, 0, stream>>>(x, xb);
  bias_prep<<<6, 256, 0, stream>>>(rpe, bias_d);
  qkv_mm<<<dim3(9, 256, 4), 256, 0, stream>>>(xb, qkv_w, qkv_b, q, k, v);
  attn<<<6144, 256, 0, stream>>>(q, k, v, bias_d, AO);
  out_mm<<<dim3(3, 256, 4), 256, 0, stream>>>(AO, out_w, out_b, out);
}